// Round 19
// baseline (163.701 us; speedup 1.0000x reference)
//
#include <hip/hip_runtime.h>
#include <hip/hip_bf16.h>
#include <hip/hip_fp16.h>

typedef _Float16 half8 __attribute__((ext_vector_type(8)));
typedef _Float16 half4 __attribute__((ext_vector_type(4)));
typedef float floatx4 __attribute__((ext_vector_type(4)));
typedef unsigned short u16;
typedef unsigned int u32;
typedef unsigned long long u64;

#define LEAKY 0.2f
#define MASKV -9.0e15f

// ---------------- Kernel A: h_ds[b][d] = (mean of 150 rows) @ wd ----------------
__global__ __launch_bounds__(256) void k_hds(const float* __restrict__ hl,
                                             const float* __restrict__ ht,
                                             const float* __restrict__ ie,
                                             const float* __restrict__ wd,
                                             float* __restrict__ hds) {
  int b = blockIdx.x, tid = threadIdx.x;
  int d = tid & 127, hh = tid >> 7;
  __shared__ float pa_[2][128];
  __shared__ float ml[128];
  __shared__ float pb_[2][128];
  const size_t base = (size_t)b * 50 * 128 + d;
  float acc = 0.f;
  for (int r = hh * 25; r < hh * 25 + 25; ++r) {
    size_t o = base + (size_t)r * 128;
    acc += hl[o] + ht[o] + ie[o];
  }
  pa_[hh][d] = acc;
  __syncthreads();
  if (hh == 0) ml[d] = (pa_[0][d] + pa_[1][d]) * (1.0f / 150.0f);
  __syncthreads();
  float o = 0.f;
  for (int k = hh * 64; k < hh * 64 + 64; ++k) o = fmaf(ml[k], wd[k * 128 + d], o);
  pb_[hh][d] = o;
  __syncthreads();
  if (hh == 0) hds[b * 128 + d] = pb_[0][d] + pb_[1][d];
}

// ---------------- Kernel B: s[w][b][i], h16[b][i][d], h16T[b][d][i] ----------------
__global__ __launch_bounds__(256) void k_prep(const float* __restrict__ h,
                                              const float* __restrict__ hds,
                                              const float* __restrict__ a0,
                                              const float* __restrict__ a1,
                                              const float* __restrict__ a2,
                                              const float* __restrict__ a3,
                                              float* __restrict__ s,
                                              u16* __restrict__ h16,
                                              u16* __restrict__ h16T) {
  int b = blockIdx.x >> 3, i0 = (blockIdx.x & 7) * 64;
  int tid = threadIdx.x, w = tid >> 6, l = tid & 63;
  __shared__ u16 tile[64][130];
  int d0 = 2 * l;
  float2 hd2 = *(const float2*)(hds + b * 128 + d0);
  float2 av0 = *(const float2*)(a0 + d0);
  float2 av1 = *(const float2*)(a1 + d0);
  float2 av2 = *(const float2*)(a2 + d0);
  float2 av3 = *(const float2*)(a3 + d0);
  for (int rr = 0; rr < 16; ++rr) {
    int il = rr * 4 + w;
    size_t row = (size_t)b * 512 + i0 + il;
    float2 hv = *(const float2*)(h + row * 128 + d0);
    _Float16 f0 = (_Float16)hv.x, f1 = (_Float16)hv.y;
    u16 u0 = __builtin_bit_cast(u16, f0), u1 = __builtin_bit_cast(u16, f1);
    tile[il][d0] = u0;
    tile[il][d0 + 1] = u1;
    *(u32*)(h16 + row * 128 + d0) = (u32)u0 | ((u32)u1 << 16);
    float t0 = hv.x * hd2.x, t1 = hv.y * hd2.y;
    float p0 = t0 * av0.x + t1 * av0.y;
    float p1 = t0 * av1.x + t1 * av1.y;
    float p2 = t0 * av2.x + t1 * av2.y;
    float p3 = t0 * av3.x + t1 * av3.y;
    for (int off = 32; off >= 1; off >>= 1) {
      p0 += __shfl_xor(p0, off);
      p1 += __shfl_xor(p1, off);
      p2 += __shfl_xor(p2, off);
      p3 += __shfl_xor(p3, off);
    }
    if (l < 4) {
      float pw = (l == 0) ? p0 : (l == 1) ? p1 : (l == 2) ? p2 : p3;
      s[((size_t)l * 64 + b) * 512 + i0 + il] = pw;
    }
  }
  __syncthreads();
  int d = tid >> 1, hf = tid & 1;
  u32 wds[16];
#pragma unroll
  for (int k = 0; k < 16; ++k) {
    u32 lo = tile[32 * hf + 2 * k][d];
    u32 hi = tile[32 * hf + 2 * k + 1][d];
    wds[k] = lo | (hi << 16);
  }
  uint4* dst = (uint4*)(h16T + ((size_t)b * 128 + d) * 512 + i0 + 32 * hf);
  dst[0] = make_uint4(wds[0], wds[1], wds[2], wds[3]);
  dst[1] = make_uint4(wds[4], wds[5], wds[6], wds[7]);
  dst[2] = make_uint4(wds[8], wds[9], wds[10], wds[11]);
  dst[3] = make_uint4(wds[12], wds[13], wds[14], wds[15]);
}

// ---------------- Kernel C: swapped-QK independent-wave fused attention ----------------
// Block = 4 waves, 16-row i-tile; wave jq owns j-quarter (128 j's = 2 t-bodies).
// R19: R18's swapped-QK structure + R16's load ordering (kfa -> vba at t-body top;
// QK waits kfa via counted vmcnt while vba flies through QK+softmax into PV).
__global__ __launch_bounds__(256, 2) void k_attn(const u16* __restrict__ h16,
                                                 const u16* __restrict__ h16T,
                                                 const float* __restrict__ s,
                                                 const int* __restrict__ adj,
                                                 const float* __restrict__ a0,
                                                 const float* __restrict__ a1,
                                                 const float* __restrict__ a2,
                                                 const float* __restrict__ a3,
                                                 float* __restrict__ out) {
  int bid = blockIdx.x;
  int wg = (bid & 7) * 256 + (bid >> 3);  // XCD swizzle (2048 % 8 == 0, bijective)
  int b = wg >> 5, i0r = (wg & 31) * 16;
  int tid = threadIdx.x, jq = tid >> 6, l = tid & 63;
  int l15 = l & 15, l4 = l >> 4;

  __shared__ u16 a16[4][128];        // a vectors, f16 (1 KB)
  __shared__ float s_lds[4][512];    // per-head s rows for this b (8 KB)
  __shared__ float mrg[4][16][132];  // all-quarter pv publish (33.8 KB)
  __shared__ float mml[4][16][2];    // all-quarter m,l (0.5 KB)

  const size_t hb16 = (size_t)b * 512 * 128;
  const size_t hTb = (size_t)b * 128 * 512;
  const int j0a = jq * 128, j0b = jq * 128 + 64;
  const int* adjrow = adj + ((size_t)(b * 512 + i0r + l15)) * 512;

  // ---- t=0 adj loads first (HBM-cold, longest latency) ----
  int4 av0[4];
#pragma unroll
  for (int C = 0; C < 4; ++C)
    av0[C] = *(const int4*)(adjrow + j0a + 16 * C + 4 * l4);

  // Q fragments (B-operand): col=l15 -> i, k=8*l4+e -> d
  half8 hf[4];
#pragma unroll
  for (int ks = 0; ks < 4; ++ks)
    hf[ks] = *(const half8*)(h16 + hb16 + (size_t)(i0r + l15) * 128 + ks * 32 + 8 * l4);

  // cooperative staging: a vectors (f16) + s rows (f32) into LDS
  if (tid < 128) {
    a16[0][tid] = __builtin_bit_cast(u16, (_Float16)a0[tid]);
    a16[1][tid] = __builtin_bit_cast(u16, (_Float16)a1[tid]);
    a16[2][tid] = __builtin_bit_cast(u16, (_Float16)a2[tid]);
    a16[3][tid] = __builtin_bit_cast(u16, (_Float16)a3[tid]);
  }
#pragma unroll
  for (int p = 0; p < 2; ++p) {
    int cid = p * 256 + tid;  // [0,512)
    int hd = cid >> 7, i4 = (cid & 127) * 4;
    *(float4*)&s_lds[hd][i4] = *(const float4*)(s + ((size_t)hd * 64 + b) * 512 + i4);
  }
  __syncthreads();

  float m = MASKV, lsum = 0.f;
  floatx4 pv[8];
#pragma unroll
  for (int dt = 0; dt < 8; ++dt) pv[dt] = (floatx4){0.f, 0.f, 0.f, 0.f};

  // helpers
  auto load_kfa = [&](int j0, half8* dst) {
#pragma unroll
    for (int ks = 0; ks < 4; ++ks)
#pragma unroll
      for (int C = 0; C < 4; ++C)
        dst[ks * 4 + C] = *(const half8*)(h16 + hb16 + (size_t)(j0 + 16 * C + l15) * 128 + ks * 32 + 8 * l4);
  };
  auto load_vba = [&](int j0, half4* dst) {
#pragma unroll
    for (int dt = 0; dt < 8; ++dt)
#pragma unroll
      for (int C = 0; C < 4; ++C)
        dst[dt * 4 + C] = *(const half4*)(h16T + hTb + (size_t)(16 * dt + l15) * 512 + j0 + 16 * C + 4 * l4);
  };
  // QK^T swapped: qk[C][e] = S[i = i0r+l15][j = j0 + 16C + 4*l4 + e]
  auto qk_select = [&](const int4* av, const half8* kfa, int j0, float x[4][4]) {
#pragma unroll
    for (int C = 0; C < 4; ++C)
#pragma unroll
      for (int e = 0; e < 4; ++e) x[C][e] = MASKV;
#pragma unroll
    for (int hd = 0; hd < 4; ++hd) {
      float si_h = s_lds[hd][i0r + l15];
      float4 sj[4];
#pragma unroll
      for (int C = 0; C < 4; ++C) sj[C] = *(const float4*)&s_lds[hd][j0 + 16 * C + 4 * l4];
      floatx4 qk[4];
#pragma unroll
      for (int C = 0; C < 4; ++C) qk[C] = (floatx4){0.f, 0.f, 0.f, 0.f};
      __builtin_amdgcn_s_setprio(1);
#pragma unroll
      for (int ks = 0; ks < 4; ++ks) {
        half8 af = *(const half8*)&a16[hd][ks * 32 + 8 * l4];
        half8 q = hf[ks] * af;
#pragma unroll
        for (int C = 0; C < 4; ++C)
          qk[C] = __builtin_amdgcn_mfma_f32_16x16x32_f16(kfa[ks * 4 + C], q, qk[C], 0, 0, 0);
      }
      __builtin_amdgcn_s_setprio(0);
#pragma unroll
      for (int C = 0; C < 4; ++C) {
        int va[4] = {av[C].x, av[C].y, av[C].z, av[C].w};
#pragma unroll
        for (int e = 0; e < 4; ++e) {
          if (va[e] == hd + 1) {
            float v = qk[C][e] + si_h + ((const float*)&sj[C])[e];
            x[C][e] = (v > 0.f) ? v : LEAKY * v;
          }
        }
      }
    }
  };
  // softmax over this 64-j tile: row i is lane-local + 2 shfl rounds across l4
  auto softmax_pack = [&](const float x[4][4], bool first, half4* pb) {
    float tmax = x[0][0];
#pragma unroll
    for (int C = 0; C < 4; ++C)
#pragma unroll
      for (int e = 0; e < 4; ++e) tmax = fmaxf(tmax, x[C][e]);
    tmax = fmaxf(tmax, __shfl_xor(tmax, 16));
    tmax = fmaxf(tmax, __shfl_xor(tmax, 32));
    float mn = first ? tmax : fmaxf(m, tmax);
    float p[4][4], ls = 0.f;
#pragma unroll
    for (int C = 0; C < 4; ++C)
#pragma unroll
      for (int e = 0; e < 4; ++e) {
        p[C][e] = __expf(x[C][e] - mn);
        ls += p[C][e];
      }
    ls += __shfl_xor(ls, 16);
    ls += __shfl_xor(ls, 32);
    if (first) {
      lsum = ls;
    } else {
      float sc = __expf(m - mn);
      lsum = lsum * sc + ls;
#pragma unroll
      for (int dt = 0; dt < 8; ++dt) pv[dt] *= sc;
    }
    m = mn;
#pragma unroll
    for (int C = 0; C < 4; ++C) {
      half4 t;
      t[0] = (_Float16)p[C][0]; t[1] = (_Float16)p[C][1];
      t[2] = (_Float16)p[C][2]; t[3] = (_Float16)p[C][3];
      pb[C] = t;
    }
  };
  // PV: A = V^T frag (row=l15->d, k=4*l4+e->j), B = P (col=l15->i, k=4*l4+e->j)
  auto pv_mfma = [&](const half4* vba, const half4* pb) {
    __builtin_amdgcn_s_setprio(1);
#pragma unroll
    for (int dt = 0; dt < 8; ++dt)
#pragma unroll
      for (int C = 0; C < 4; ++C)
        pv[dt] = __builtin_amdgcn_mfma_f32_16x16x16f16(vba[dt * 4 + C], pb[C], pv[dt], 0, 0, 0);
    __builtin_amdgcn_s_setprio(0);
  };

  half8 kfa[16];
  half4 vba[32], pb[4];
  float x[4][4];

  // ---------- t = 0 : kfa then vba at top; QK waits kfa (counted vmcnt), vba flies ----------
  load_kfa(j0a, kfa);
  load_vba(j0a, vba);
  qk_select(av0, kfa, j0a, x);
  // t=1 adj loads fly under softmax+PV of t=0
  int4 av1[4];
#pragma unroll
  for (int C = 0; C < 4; ++C)
    av1[C] = *(const int4*)(adjrow + j0b + 16 * C + 4 * l4);
  softmax_pack(x, true, pb);
  pv_mfma(vba, pb);

  // ---------- t = 1 ----------
  load_kfa(j0b, kfa);
  load_vba(j0b, vba);
  qk_select(av1, kfa, j0b, x);
  softmax_pack(x, false, pb);
  pv_mfma(vba, pb);

  // ---- publish: pv lane l15 = i, reg (dt,e) + l4 = d = 16*dt + 4*l4 + e ----
#pragma unroll
  for (int dt = 0; dt < 8; ++dt)
    *(floatx4*)&mrg[jq][l15][16 * dt + 4 * l4] = pv[dt];
  if (l4 == 0) {
    mml[jq][l15][0] = m;
    mml[jq][l15][1] = lsum;
  }
  __syncthreads();

  // ---- cooperative 4-way merge + coalesced write (all 256 threads) ----
#pragma unroll
  for (int p2 = 0; p2 < 2; ++p2) {
    int i = (tid >> 5) + 8 * p2;
    int dc = (tid & 31) * 4;
    float m0 = mml[0][i][0], m1 = mml[1][i][0], m2 = mml[2][i][0], m3 = mml[3][i][0];
    float M = fmaxf(fmaxf(m0, m1), fmaxf(m2, m3));
    float w0 = __expf(m0 - M), w1 = __expf(m1 - M), w2 = __expf(m2 - M), w3 = __expf(m3 - M);
    float L = mml[0][i][1] * w0 + mml[1][i][1] * w1 + mml[2][i][1] * w2 + mml[3][i][1] * w3;
    float inv = 1.0f / L;
    w0 *= inv; w1 *= inv; w2 *= inv; w3 *= inv;
    float4 v0 = *(float4*)&mrg[0][i][dc];
    float4 v1 = *(float4*)&mrg[1][i][dc];
    float4 v2 = *(float4*)&mrg[2][i][dc];
    float4 v3 = *(float4*)&mrg[3][i][dc];
    float4 o;
    o.x = v0.x * w0 + v1.x * w1 + v2.x * w2 + v3.x * w3;
    o.y = v0.y * w0 + v1.y * w1 + v2.y * w2 + v3.y * w3;
    o.z = v0.z * w0 + v1.z * w1 + v2.z * w2 + v3.z * w3;
    o.w = v0.w * w0 + v1.w * w1 + v2.w * w2 + v3.w * w3;
    *(float4*)(out + ((size_t)b * 512 + i0r + i) * 128 + dc) = o;
  }
}

extern "C" void kernel_launch(void* const* d_in, const int* in_sizes, int n_in,
                              void* d_out, int out_size, void* d_ws, size_t ws_size,
                              hipStream_t stream) {
  const float* hl = (const float*)d_in[0];
  const float* ht = (const float*)d_in[1];
  const float* ie = (const float*)d_in[2];
  const float* h  = (const float*)d_in[3];
  const int* adj  = (const int*)d_in[4];
  const float* wd = (const float*)d_in[5];
  const float* a0 = (const float*)d_in[6];
  const float* a1 = (const float*)d_in[7];
  const float* a2 = (const float*)d_in[8];
  const float* a3 = (const float*)d_in[9];

  // ws layout (~16.6 MB)
  float* hds  = (float*)d_ws;                   // 32 KB
  float* s    = (float*)((char*)d_ws + 32768);  // [4][64][512] = 512 KB
  u16* h16    = (u16*)((char*)d_ws + 557056);   // 8 MB
  u16* h16T   = (u16*)((char*)d_ws + 8945664);  // 8 MB
  float* o    = (float*)d_out;

  k_hds<<<64, 256, 0, stream>>>(hl, ht, ie, wd, hds);
  k_prep<<<512, 256, 0, stream>>>(h, hds, a0, a1, a2, a3, s, h16, h16T);
  k_attn<<<2048, 256, 0, stream>>>(h16, h16T, s, adj, a0, a1, a2, a3, o);
}

// Round 20
// 126.910 us; speedup vs baseline: 1.2899x; 1.2899x over previous
//
#include <hip/hip_runtime.h>
#include <hip/hip_bf16.h>
#include <hip/hip_fp16.h>

typedef _Float16 half8 __attribute__((ext_vector_type(8)));
typedef _Float16 half4 __attribute__((ext_vector_type(4)));
typedef float floatx4 __attribute__((ext_vector_type(4)));
typedef unsigned short u16;
typedef unsigned int u32;
typedef unsigned long long u64;

#define LEAKY 0.2f
#define MASKV -9.0e15f

// ---------------- Kernel A: h_ds[b][d] = (mean of 150 rows) @ wd ----------------
__global__ __launch_bounds__(256) void k_hds(const float* __restrict__ hl,
                                             const float* __restrict__ ht,
                                             const float* __restrict__ ie,
                                             const float* __restrict__ wd,
                                             float* __restrict__ hds) {
  int b = blockIdx.x, tid = threadIdx.x;
  int d = tid & 127, hh = tid >> 7;
  __shared__ float pa_[2][128];
  __shared__ float ml[128];
  __shared__ float pb_[2][128];
  const size_t base = (size_t)b * 50 * 128 + d;
  float acc = 0.f;
  for (int r = hh * 25; r < hh * 25 + 25; ++r) {
    size_t o = base + (size_t)r * 128;
    acc += hl[o] + ht[o] + ie[o];
  }
  pa_[hh][d] = acc;
  __syncthreads();
  if (hh == 0) ml[d] = (pa_[0][d] + pa_[1][d]) * (1.0f / 150.0f);
  __syncthreads();
  float o = 0.f;
  for (int k = hh * 64; k < hh * 64 + 64; ++k) o = fmaf(ml[k], wd[k * 128 + d], o);
  pb_[hh][d] = o;
  __syncthreads();
  if (hh == 0) hds[b * 128 + d] = pb_[0][d] + pb_[1][d];
}

// ---------------- Kernel B: s[w][b][i], h16[b][i][d], h16T[b][d][i] ----------------
__global__ __launch_bounds__(256) void k_prep(const float* __restrict__ h,
                                              const float* __restrict__ hds,
                                              const float* __restrict__ a0,
                                              const float* __restrict__ a1,
                                              const float* __restrict__ a2,
                                              const float* __restrict__ a3,
                                              float* __restrict__ s,
                                              u16* __restrict__ h16,
                                              u16* __restrict__ h16T) {
  int b = blockIdx.x >> 3, i0 = (blockIdx.x & 7) * 64;
  int tid = threadIdx.x, w = tid >> 6, l = tid & 63;
  __shared__ u16 tile[64][130];
  int d0 = 2 * l;
  float2 hd2 = *(const float2*)(hds + b * 128 + d0);
  float2 av0 = *(const float2*)(a0 + d0);
  float2 av1 = *(const float2*)(a1 + d0);
  float2 av2 = *(const float2*)(a2 + d0);
  float2 av3 = *(const float2*)(a3 + d0);
  for (int rr = 0; rr < 16; ++rr) {
    int il = rr * 4 + w;
    size_t row = (size_t)b * 512 + i0 + il;
    float2 hv = *(const float2*)(h + row * 128 + d0);
    _Float16 f0 = (_Float16)hv.x, f1 = (_Float16)hv.y;
    u16 u0 = __builtin_bit_cast(u16, f0), u1 = __builtin_bit_cast(u16, f1);
    tile[il][d0] = u0;
    tile[il][d0 + 1] = u1;
    *(u32*)(h16 + row * 128 + d0) = (u32)u0 | ((u32)u1 << 16);
    float t0 = hv.x * hd2.x, t1 = hv.y * hd2.y;
    float p0 = t0 * av0.x + t1 * av0.y;
    float p1 = t0 * av1.x + t1 * av1.y;
    float p2 = t0 * av2.x + t1 * av2.y;
    float p3 = t0 * av3.x + t1 * av3.y;
    for (int off = 32; off >= 1; off >>= 1) {
      p0 += __shfl_xor(p0, off);
      p1 += __shfl_xor(p1, off);
      p2 += __shfl_xor(p2, off);
      p3 += __shfl_xor(p3, off);
    }
    if (l < 4) {
      float pw = (l == 0) ? p0 : (l == 1) ? p1 : (l == 2) ? p2 : p3;
      s[((size_t)l * 64 + b) * 512 + i0 + il] = pw;
    }
  }
  __syncthreads();
  int d = tid >> 1, hf = tid & 1;
  u32 wds[16];
#pragma unroll
  for (int k = 0; k < 16; ++k) {
    u32 lo = tile[32 * hf + 2 * k][d];
    u32 hi = tile[32 * hf + 2 * k + 1][d];
    wds[k] = lo | (hi << 16);
  }
  uint4* dst = (uint4*)(h16T + ((size_t)b * 128 + d) * 512 + i0 + 32 * hf);
  dst[0] = make_uint4(wds[0], wds[1], wds[2], wds[3]);
  dst[1] = make_uint4(wds[4], wds[5], wds[6], wds[7]);
  dst[2] = make_uint4(wds[8], wds[9], wds[10], wds[11]);
  dst[3] = make_uint4(wds[12], wds[13], wds[14], wds[15]);
}

// ---------------- Kernel C: swapped-QK independent-wave fused attention ----------------
// Block = 4 waves, 16-row i-tile; wave jq owns j-quarter (128 j's = 2 t-bodies).
// R20: split-V prefetch — vba half0 issued with kfa (flies through QK); half1 issued
// after QK (kfa regs dead, reused), lands under softmax+PV0. No full K+V coresidency.
__global__ __launch_bounds__(256, 2) void k_attn(const u16* __restrict__ h16,
                                                 const u16* __restrict__ h16T,
                                                 const float* __restrict__ s,
                                                 const int* __restrict__ adj,
                                                 const float* __restrict__ a0,
                                                 const float* __restrict__ a1,
                                                 const float* __restrict__ a2,
                                                 const float* __restrict__ a3,
                                                 float* __restrict__ out) {
  int bid = blockIdx.x;
  int wg = (bid & 7) * 256 + (bid >> 3);  // XCD swizzle (2048 % 8 == 0, bijective)
  int b = wg >> 5, i0r = (wg & 31) * 16;
  int tid = threadIdx.x, jq = tid >> 6, l = tid & 63;
  int l15 = l & 15, l4 = l >> 4;

  __shared__ u16 a16[4][128];        // a vectors, f16 (1 KB)
  __shared__ float s_lds[4][512];    // per-head s rows for this b (8 KB)
  __shared__ float mrg[4][16][132];  // all-quarter pv publish (33.8 KB)
  __shared__ float mml[4][16][2];    // all-quarter m,l (0.5 KB)

  const size_t hb16 = (size_t)b * 512 * 128;
  const size_t hTb = (size_t)b * 128 * 512;
  const int j0a = jq * 128, j0b = jq * 128 + 64;
  const int* adjrow = adj + ((size_t)(b * 512 + i0r + l15)) * 512;

  // ---- t=0 adj loads first (HBM-cold, longest latency) ----
  int4 av0[4];
#pragma unroll
  for (int C = 0; C < 4; ++C)
    av0[C] = *(const int4*)(adjrow + j0a + 16 * C + 4 * l4);

  // Q fragments (B-operand): col=l15 -> i, k=8*l4+e -> d
  half8 hf[4];
#pragma unroll
  for (int ks = 0; ks < 4; ++ks)
    hf[ks] = *(const half8*)(h16 + hb16 + (size_t)(i0r + l15) * 128 + ks * 32 + 8 * l4);

  // cooperative staging: a vectors (f16) + s rows (f32) into LDS
  if (tid < 128) {
    a16[0][tid] = __builtin_bit_cast(u16, (_Float16)a0[tid]);
    a16[1][tid] = __builtin_bit_cast(u16, (_Float16)a1[tid]);
    a16[2][tid] = __builtin_bit_cast(u16, (_Float16)a2[tid]);
    a16[3][tid] = __builtin_bit_cast(u16, (_Float16)a3[tid]);
  }
#pragma unroll
  for (int p = 0; p < 2; ++p) {
    int cid = p * 256 + tid;  // [0,512)
    int hd = cid >> 7, i4 = (cid & 127) * 4;
    *(float4*)&s_lds[hd][i4] = *(const float4*)(s + ((size_t)hd * 64 + b) * 512 + i4);
  }
  __syncthreads();

  float m = MASKV, lsum = 0.f;
  floatx4 pv[8];
#pragma unroll
  for (int dt = 0; dt < 8; ++dt) pv[dt] = (floatx4){0.f, 0.f, 0.f, 0.f};

  // helpers
  auto load_kfa = [&](int j0, half8* dst) {
#pragma unroll
    for (int ks = 0; ks < 4; ++ks)
#pragma unroll
      for (int C = 0; C < 4; ++C)
        dst[ks * 4 + C] = *(const half8*)(h16 + hb16 + (size_t)(j0 + 16 * C + l15) * 128 + ks * 32 + 8 * l4);
  };
  // half hv of V fragments: dt in [4*hv, 4*hv+4)
  auto load_vba_half = [&](int j0, int hv, half4* dst) {
#pragma unroll
    for (int dt2 = 0; dt2 < 4; ++dt2)
#pragma unroll
      for (int C = 0; C < 4; ++C)
        dst[dt2 * 4 + C] = *(const half4*)(h16T + hTb + (size_t)(16 * (4 * hv + dt2) + l15) * 512 + j0 + 16 * C + 4 * l4);
  };
  // QK^T swapped: qk[C][e] = S[i = i0r+l15][j = j0 + 16C + 4*l4 + e]
  auto qk_select = [&](const int4* av, const half8* kfa, int j0, float x[4][4]) {
#pragma unroll
    for (int C = 0; C < 4; ++C)
#pragma unroll
      for (int e = 0; e < 4; ++e) x[C][e] = MASKV;
#pragma unroll
    for (int hd = 0; hd < 4; ++hd) {
      float si_h = s_lds[hd][i0r + l15];
      float4 sj[4];
#pragma unroll
      for (int C = 0; C < 4; ++C) sj[C] = *(const float4*)&s_lds[hd][j0 + 16 * C + 4 * l4];
      floatx4 qk[4];
#pragma unroll
      for (int C = 0; C < 4; ++C) qk[C] = (floatx4){0.f, 0.f, 0.f, 0.f};
      __builtin_amdgcn_s_setprio(1);
#pragma unroll
      for (int ks = 0; ks < 4; ++ks) {
        half8 af = *(const half8*)&a16[hd][ks * 32 + 8 * l4];
        half8 q = hf[ks] * af;
#pragma unroll
        for (int C = 0; C < 4; ++C)
          qk[C] = __builtin_amdgcn_mfma_f32_16x16x32_f16(kfa[ks * 4 + C], q, qk[C], 0, 0, 0);
      }
      __builtin_amdgcn_s_setprio(0);
#pragma unroll
      for (int C = 0; C < 4; ++C) {
        int va[4] = {av[C].x, av[C].y, av[C].z, av[C].w};
#pragma unroll
        for (int e = 0; e < 4; ++e) {
          if (va[e] == hd + 1) {
            float v = qk[C][e] + si_h + ((const float*)&sj[C])[e];
            x[C][e] = (v > 0.f) ? v : LEAKY * v;
          }
        }
      }
    }
  };
  // softmax over this 64-j tile: row i is lane-local + 2 shfl rounds across l4
  auto softmax_pack = [&](const float x[4][4], bool first, half4* pb) {
    float tmax = x[0][0];
#pragma unroll
    for (int C = 0; C < 4; ++C)
#pragma unroll
      for (int e = 0; e < 4; ++e) tmax = fmaxf(tmax, x[C][e]);
    tmax = fmaxf(tmax, __shfl_xor(tmax, 16));
    tmax = fmaxf(tmax, __shfl_xor(tmax, 32));
    float mn = first ? tmax : fmaxf(m, tmax);
    float p[4][4], ls = 0.f;
#pragma unroll
    for (int C = 0; C < 4; ++C)
#pragma unroll
      for (int e = 0; e < 4; ++e) {
        p[C][e] = __expf(x[C][e] - mn);
        ls += p[C][e];
      }
    ls += __shfl_xor(ls, 16);
    ls += __shfl_xor(ls, 32);
    if (first) {
      lsum = ls;
    } else {
      float sc = __expf(m - mn);
      lsum = lsum * sc + ls;
#pragma unroll
      for (int dt = 0; dt < 8; ++dt) pv[dt] *= sc;
    }
    m = mn;
#pragma unroll
    for (int C = 0; C < 4; ++C) {
      half4 t;
      t[0] = (_Float16)p[C][0]; t[1] = (_Float16)p[C][1];
      t[2] = (_Float16)p[C][2]; t[3] = (_Float16)p[C][3];
      pb[C] = t;
    }
  };
  // PV half hv: pv[4*hv + dt2] over the 4 V fragments of that half
  auto pv_mfma_half = [&](const half4* vbah, const half4* pb, int hv) {
    __builtin_amdgcn_s_setprio(1);
#pragma unroll
    for (int dt2 = 0; dt2 < 4; ++dt2)
#pragma unroll
      for (int C = 0; C < 4; ++C)
        pv[4 * hv + dt2] = __builtin_amdgcn_mfma_f32_16x16x16f16(vbah[dt2 * 4 + C], pb[C], pv[4 * hv + dt2], 0, 0, 0);
    __builtin_amdgcn_s_setprio(0);
  };

  half8 kfa[16];
  half4 vba0[16], vba1[16], pb[4];
  float x[4][4];

  // ---------- t = 0 ----------
  load_kfa(j0a, kfa);
  load_vba_half(j0a, 0, vba0);       // flies through QK
  qk_select(av0, kfa, j0a, x);       // kfa dead after this
  load_vba_half(j0a, 1, vba1);       // reuses kfa regs; lands under softmax+PV0
  int4 av1[4];
#pragma unroll
  for (int C = 0; C < 4; ++C)
    av1[C] = *(const int4*)(adjrow + j0b + 16 * C + 4 * l4);
  softmax_pack(x, true, pb);
  pv_mfma_half(vba0, pb, 0);
  pv_mfma_half(vba1, pb, 1);

  // ---------- t = 1 ----------
  load_kfa(j0b, kfa);
  load_vba_half(j0b, 0, vba0);
  qk_select(av1, kfa, j0b, x);
  load_vba_half(j0b, 1, vba1);
  softmax_pack(x, false, pb);
  pv_mfma_half(vba0, pb, 0);
  pv_mfma_half(vba1, pb, 1);

  // ---- publish: pv lane l15 = i, reg (dt,e) + l4 = d = 16*dt + 4*l4 + e ----
#pragma unroll
  for (int dt = 0; dt < 8; ++dt)
    *(floatx4*)&mrg[jq][l15][16 * dt + 4 * l4] = pv[dt];
  if (l4 == 0) {
    mml[jq][l15][0] = m;
    mml[jq][l15][1] = lsum;
  }
  __syncthreads();

  // ---- cooperative 4-way merge + coalesced write (all 256 threads) ----
#pragma unroll
  for (int p2 = 0; p2 < 2; ++p2) {
    int i = (tid >> 5) + 8 * p2;
    int dc = (tid & 31) * 4;
    float m0 = mml[0][i][0], m1 = mml[1][i][0], m2 = mml[2][i][0], m3 = mml[3][i][0];
    float M = fmaxf(fmaxf(m0, m1), fmaxf(m2, m3));
    float w0 = __expf(m0 - M), w1 = __expf(m1 - M), w2 = __expf(m2 - M), w3 = __expf(m3 - M);
    float L = mml[0][i][1] * w0 + mml[1][i][1] * w1 + mml[2][i][1] * w2 + mml[3][i][1] * w3;
    float inv = 1.0f / L;
    w0 *= inv; w1 *= inv; w2 *= inv; w3 *= inv;
    float4 v0 = *(float4*)&mrg[0][i][dc];
    float4 v1 = *(float4*)&mrg[1][i][dc];
    float4 v2 = *(float4*)&mrg[2][i][dc];
    float4 v3 = *(float4*)&mrg[3][i][dc];
    float4 o;
    o.x = v0.x * w0 + v1.x * w1 + v2.x * w2 + v3.x * w3;
    o.y = v0.y * w0 + v1.y * w1 + v2.y * w2 + v3.y * w3;
    o.z = v0.z * w0 + v1.z * w1 + v2.z * w2 + v3.z * w3;
    o.w = v0.w * w0 + v1.w * w1 + v2.w * w2 + v3.w * w3;
    *(float4*)(out + ((size_t)b * 512 + i0r + i) * 128 + dc) = o;
  }
}

extern "C" void kernel_launch(void* const* d_in, const int* in_sizes, int n_in,
                              void* d_out, int out_size, void* d_ws, size_t ws_size,
                              hipStream_t stream) {
  const float* hl = (const float*)d_in[0];
  const float* ht = (const float*)d_in[1];
  const float* ie = (const float*)d_in[2];
  const float* h  = (const float*)d_in[3];
  const int* adj  = (const int*)d_in[4];
  const float* wd = (const float*)d_in[5];
  const float* a0 = (const float*)d_in[6];
  const float* a1 = (const float*)d_in[7];
  const float* a2 = (const float*)d_in[8];
  const float* a3 = (const float*)d_in[9];

  // ws layout (~16.6 MB)
  float* hds  = (float*)d_ws;                   // 32 KB
  float* s    = (float*)((char*)d_ws + 32768);  // [4][64][512] = 512 KB
  u16* h16    = (u16*)((char*)d_ws + 557056);   // 8 MB
  u16* h16T   = (u16*)((char*)d_ws + 8945664);  // 8 MB
  float* o    = (float*)d_out;

  k_hds<<<64, 256, 0, stream>>>(hl, ht, ie, wd, hds);
  k_prep<<<512, 256, 0, stream>>>(h, hds, a0, a1, a2, a3, s, h16, h16T);
  k_attn<<<2048, 256, 0, stream>>>(h16, h16T, s, adj, a0, a1, a2, a3, o);
}